// Round 7
// baseline (400.161 us; speedup 1.0000x reference)
//
#include <hip/hip_runtime.h>
#include <math.h>

typedef float f4 __attribute__((ext_vector_type(4)));
typedef float f32x4 __attribute__((ext_vector_type(4)));
typedef short s8 __attribute__((ext_vector_type(8)));  // 8 bf16 (4 VGPRs)
typedef short s4 __attribute__((ext_vector_type(4)));  // 4 bf16 (2 VGPRs)

static constexpr int N = 50000;
static constexpr int E = 800000;
static constexpr int D = 128;
static constexpr int SCAN_NB = (N + 255) / 256;        // 196
static constexpr int MBLK = 64;                        // gemm rows/block
static constexpr int GRID_M = (N + MBLK - 1) / MBLK;   // 782
static constexpr int N_PAD = GRID_M * MBLK;            // 50048
static constexpr int WT_PITCH = 136;                   // LDS pad: 272 B rows, 16B-aligned

__device__ inline unsigned short f32_bf16_rne(float x) {
    unsigned u = __float_as_uint(x);
    return (unsigned short)((u + 0x7FFF + ((u >> 16) & 1)) >> 16);
}
__device__ inline float bf16_f32(unsigned short h) {
    return __uint_as_float((unsigned)h << 16);
}

// --- int degree histogram ---
__global__ void deg_kernel(const int* __restrict__ src, const int* __restrict__ dst,
                           int* __restrict__ deg_out, int* __restrict__ deg_in) {
    int e = blockIdx.x * 256 + threadIdx.x;
    if (e < E) {
        atomicAdd(&deg_out[src[e]], 1);
        atomicAdd(&deg_in[dst[e]], 1);
    }
}

// --- norms from int degrees ---
__global__ void norm_kernel(const int* __restrict__ deg_out, const int* __restrict__ deg_in,
                            float* __restrict__ norm_src, float* __restrict__ norm_dst) {
    int i = blockIdx.x * 256 + threadIdx.x;
    if (i < N) {
        norm_src[i] = rsqrtf(fmaxf((float)deg_out[i], 1.0f));
        norm_dst[i] = rsqrtf(fmaxf((float)deg_in[i], 1.0f));
    }
}

// --- scan pass 1: per-block sums ---
__global__ __launch_bounds__(256) void scan_bsum_kernel(const int* __restrict__ deg,
                                                        int* __restrict__ bsums) {
    int i = blockIdx.x * 256 + threadIdx.x;
    int v = (i < N) ? deg[i] : 0;
#pragma unroll
    for (int off = 1; off < 64; off <<= 1) v += __shfl_xor(v, off, 64);
    __shared__ int ws[4];
    if ((threadIdx.x & 63) == 0) ws[threadIdx.x >> 6] = v;
    __syncthreads();
    if (threadIdx.x == 0) bsums[blockIdx.x] = ws[0] + ws[1] + ws[2] + ws[3];
}

// --- scan pass 2: exclusive scan of block sums ---
__global__ __launch_bounds__(256) void scan_bsums_kernel(int* __restrict__ bsums) {
    __shared__ int s[256];
    int t = threadIdx.x;
    s[t] = (t < SCAN_NB) ? bsums[t] : 0;
    __syncthreads();
    for (int off = 1; off < 256; off <<= 1) {
        int v = (t >= off) ? s[t - off] : 0;
        __syncthreads();
        s[t] += v;
        __syncthreads();
    }
    if (t < SCAN_NB) bsums[t] = (t == 0) ? 0 : s[t - 1];
}

// --- scan pass 3: rescan + offset -> row_ptr ---
__global__ __launch_bounds__(256) void scan_final_kernel(const int* __restrict__ deg,
                                                         const int* __restrict__ bsums,
                                                         int* __restrict__ row_ptr) {
    __shared__ int s[256];
    int b = blockIdx.x, t = threadIdx.x;
    int i = b * 256 + t;
    s[t] = (i < N) ? deg[i] : 0;
    __syncthreads();
    for (int off = 1; off < 256; off <<= 1) {
        int v = (t >= off) ? s[t - off] : 0;
        __syncthreads();
        s[t] += v;
        __syncthreads();
    }
    if (i < N) row_ptr[i + 1] = s[t] + bsums[b];
    if (i == 0) row_ptr[0] = 0;
}

// --- csr_src fill ---
__global__ void fill_kernel(const int* __restrict__ src, const int* __restrict__ dst,
                            const int* __restrict__ row_ptr, int* __restrict__ cursor,
                            int* __restrict__ csr_src) {
    int e = blockIdx.x * 256 + threadIdx.x;
    if (e < E) {
        int d = dst[e];
        int pos = row_ptr[d] + atomicAdd(&cursor[d], 1);
        csr_src[pos] = src[e];
    }
}

// --- hs[i] = emb[batch[i]] * norm_src[i] ---
__global__ void gather_kernel(const int* __restrict__ batch, const float* __restrict__ emb,
                              const float* __restrict__ norm_src, float* __restrict__ hs) {
    int gid = blockIdx.x * 256 + threadIdx.x;
    int i = gid >> 5;
    int c = (gid & 31) << 2;
    if (i < N) {
        float s = norm_src[i];
        f4 v = *(const f4*)(emb + (size_t)batch[i] * D + c);
        *(f4*)(hs + (size_t)i * D + c) = v * s;
    }
}

// --- agg: gather-sum hs rows, then split result to bf16 hi/lo for the MFMA gemm ---
__global__ void agg_kernel(const int* __restrict__ row_ptr, const int* __restrict__ csr_src,
                           const float* __restrict__ hs,
                           short* __restrict__ agg_h, short* __restrict__ agg_l) {
    int gid = blockIdx.x * 256 + threadIdx.x;
    int node = gid >> 6;
    if (node >= N) return;
    int lane = threadIdx.x & 63;
    int grp = lane >> 5;
    int col = (lane & 31) << 2;
    int beg = row_ptr[node], end = row_ptr[node + 1];

    f4 a0 = (f4)0.0f, a1 = (f4)0.0f, a2 = (f4)0.0f, a3 = (f4)0.0f;
    f4 a4 = (f4)0.0f, a5 = (f4)0.0f, a6 = (f4)0.0f, a7 = (f4)0.0f;
    int e = beg + grp;
    for (; e + 14 < end; e += 16) {
        int s0 = csr_src[e];
        int s1 = csr_src[e + 2];
        int s2 = csr_src[e + 4];
        int s3 = csr_src[e + 6];
        int s4 = csr_src[e + 8];
        int s5 = csr_src[e + 10];
        int s6 = csr_src[e + 12];
        int s7 = csr_src[e + 14];
        a0 += *(const f4*)(hs + (size_t)s0 * D + col);
        a1 += *(const f4*)(hs + (size_t)s1 * D + col);
        a2 += *(const f4*)(hs + (size_t)s2 * D + col);
        a3 += *(const f4*)(hs + (size_t)s3 * D + col);
        a4 += *(const f4*)(hs + (size_t)s4 * D + col);
        a5 += *(const f4*)(hs + (size_t)s5 * D + col);
        a6 += *(const f4*)(hs + (size_t)s6 * D + col);
        a7 += *(const f4*)(hs + (size_t)s7 * D + col);
    }
    for (; e < end; e += 2)
        a0 += *(const f4*)(hs + (size_t)csr_src[e] * D + col);
    a0 += a1; a2 += a3; a4 += a5; a6 += a7;
    a0 += a2; a4 += a6;
    a0 += a4;

    f4 o;
#pragma unroll
    for (int j = 0; j < 4; ++j)
        o[j] = a0[j] + __shfl_xor(a0[j], 32, 64);
    if (grp == 0) {
        s4 oh, ol;
#pragma unroll
        for (int j = 0; j < 4; ++j) {
            unsigned short h = f32_bf16_rne(o[j]);
            oh[j] = (short)h;
            ol[j] = (short)f32_bf16_rne(o[j] - bf16_f32(h));
        }
        *(s4*)(agg_h + (size_t)node * D + col) = oh;
        *(s4*)(agg_l + (size_t)node * D + col) = ol;
    }
}

// --- W prep: wt[layer][hi/lo][n][k] = bf16 split of W[k][n] (transposed, n-major) ---
__global__ void wprep_kernel(const float* __restrict__ W1, const float* __restrict__ W2,
                             const float* __restrict__ W3, short* __restrict__ wt) {
    int idx = blockIdx.x * 256 + threadIdx.x;
    if (idx >= 3 * D * D) return;
    int l = idx >> 14;          // layer
    int e = idx & (D * D - 1);
    int n = e >> 7, k = e & 127;
    const float* W = (l == 0) ? W1 : ((l == 1) ? W2 : W3);
    float w = W[(size_t)k * D + n];
    unsigned short h = f32_bf16_rne(w);
    unsigned short lo = f32_bf16_rne(w - bf16_f32(h));
    wt[(size_t)l * 2 * D * D + (size_t)n * D + k] = (short)h;
    wt[(size_t)l * 2 * D * D + D * D + (size_t)n * D + k] = (short)lo;
}

// --- MFMA GEMM: out[r, cb*64+:64] = relu(nd[r]*(A[r]@W[:,cols]) + b) * post[r]
// A pre-split to bf16 hi/lo by agg_kernel; W staged hi/lo bf16 in LDS.
// 3-term split: C = Ah@Wh + Al@Wh + Ah@Wl  (error ~2^-18 rel).
__global__ __launch_bounds__(256, 2) void gemm_mfma_kernel(
    const short* __restrict__ Ah, const short* __restrict__ Al,
    const short* __restrict__ wth,
    const float* __restrict__ bias, const float* __restrict__ norm_dst,
    const float* __restrict__ post, float* __restrict__ out) {
    __shared__ short wt_h[64 * WT_PITCH];
    __shared__ short wt_l[64 * WT_PITCH];

    int tid = threadIdx.x;
    int cb = blockIdx.y;                        // column half
    const short* gh = wth + (size_t)cb * 64 * D;          // hi rows [cb*64, +64)
    const short* gl = wth + (size_t)D * D + (size_t)cb * 64 * D;

#pragma unroll
    for (int it = 0; it < 4; ++it) {
        int c = tid + it * 256;                 // chunk of 8 shorts (1024 chunks)
        int n = c >> 4, kc = c & 15;
        *(s8*)(&wt_h[n * WT_PITCH + kc * 8]) = *(const s8*)(gh + (size_t)n * D + kc * 8);
        *(s8*)(&wt_l[n * WT_PITCH + kc * 8]) = *(const s8*)(gl + (size_t)n * D + kc * 8);
    }
    __syncthreads();

    int wv = tid >> 6;
    int lane = tid & 63;
    int lg = lane >> 4;                         // lane group 0..3 (k-slice)
    int lr = lane & 15;                         // row/col within 16-tile

    int arow = blockIdx.x * 64 + wv * 16 + lr;  // A row for this lane's fragments
    const short* ahp = Ah + (size_t)arow * D;
    const short* alp = Al + (size_t)arow * D;

    f32x4 acc[4];
#pragma unroll
    for (int nt = 0; nt < 4; ++nt) acc[nt] = (f32x4)0.0f;

#pragma unroll
    for (int kt = 0; kt < 4; ++kt) {
        int ko = kt * 32 + lg * 8;
        s8 ah = *(const s8*)(ahp + ko);
        s8 al = *(const s8*)(alp + ko);
#pragma unroll
        for (int nt = 0; nt < 4; ++nt) {
            int bidx = (nt * 16 + lr) * WT_PITCH + ko;
            s8 bh = *(const s8*)(&wt_h[bidx]);
            s8 bl = *(const s8*)(&wt_l[bidx]);
            acc[nt] = __builtin_amdgcn_mfma_f32_16x16x32_bf16(ah, bh, acc[nt], 0, 0, 0);
            acc[nt] = __builtin_amdgcn_mfma_f32_16x16x32_bf16(al, bh, acc[nt], 0, 0, 0);
            acc[nt] = __builtin_amdgcn_mfma_f32_16x16x32_bf16(ah, bl, acc[nt], 0, 0, 0);
        }
    }

    // epilogue: C[row = wv*16 + lg*4 + i][col = nt*16 + lr]
    int r0 = blockIdx.x * 64 + wv * 16 + lg * 4;
    float nd[4], ps[4];
#pragma unroll
    for (int i = 0; i < 4; ++i) {
        int gr = r0 + i;
        nd[i] = (gr < N) ? norm_dst[gr] : 0.0f;
        ps[i] = (gr < N) ? (post ? post[gr] : 1.0f) : 0.0f;
    }
#pragma unroll
    for (int nt = 0; nt < 4; ++nt) {
        int col = cb * 64 + nt * 16 + lr;
        float bv = bias[col];
#pragma unroll
        for (int i = 0; i < 4; ++i) {
            int gr = r0 + i;
            if (gr < N) {
                float v = fmaxf(acc[nt][i] * nd[i] + bv, 0.0f) * ps[i];
                out[(size_t)gr * D + col] = v;
            }
        }
    }
}

extern "C" void kernel_launch(void* const* d_in, const int* in_sizes, int n_in,
                              void* d_out, int out_size, void* d_ws, size_t ws_size,
                              hipStream_t stream) {
    const int*   batch = (const int*)d_in[0];
    const int*   src   = (const int*)d_in[1];
    const int*   dst   = (const int*)d_in[2];
    const float* emb   = (const float*)d_in[3];
    const float* W1    = (const float*)d_in[4];
    const float* b1    = (const float*)d_in[5];
    const float* W2    = (const float*)d_in[6];
    const float* b2    = (const float*)d_in[7];
    const float* W3    = (const float*)d_in[8];
    const float* b3    = (const float*)d_in[9];
    float* out = (float*)d_out;

    // ws layout (4B elems): norm_src[N] | norm_dst[N] | row_ptr[N+1] | csr_src[E]
    //                       | hs[N_PAD*D] | agg_h[N_PAD*D shorts] | agg_l[N_PAD*D shorts]
    //                       | wt (3*2*D*D shorts)
    // transient ints (deg_out, deg_in, cursor, bsums) alias the agg_h region.
    float* norm_src = (float*)d_ws;
    float* norm_dst = norm_src + N;
    int*   row_ptr  = (int*)(norm_dst + N);
    int*   csr_src  = row_ptr + (N + 1);
    float* hs       = (float*)(csr_src + E) + 3;  // 16B alignment
    short* agg_h    = (short*)(hs + (size_t)N_PAD * D);
    short* agg_l    = agg_h + (size_t)N_PAD * D;
    short* wt       = agg_l + (size_t)N_PAD * D;
    int*   deg_out  = (int*)agg_h;   // transient
    int*   deg_in   = deg_out + N;
    int*   cursor   = deg_in + N;
    int*   bsums    = cursor + N;

    hipMemsetAsync(deg_out, 0, 3 * (size_t)N * sizeof(int), stream);
    deg_kernel<<<(E + 255) / 256, 256, 0, stream>>>(src, dst, deg_out, deg_in);
    norm_kernel<<<(N + 255) / 256, 256, 0, stream>>>(deg_out, deg_in, norm_src, norm_dst);
    scan_bsum_kernel<<<SCAN_NB, 256, 0, stream>>>(deg_in, bsums);
    scan_bsums_kernel<<<1, 256, 0, stream>>>(bsums);
    scan_final_kernel<<<SCAN_NB, 256, 0, stream>>>(deg_in, bsums, row_ptr);
    fill_kernel<<<(E + 255) / 256, 256, 0, stream>>>(src, dst, row_ptr, cursor, csr_src);
    gather_kernel<<<((size_t)N * 32 + 255) / 256, 256, 0, stream>>>(batch, emb, norm_src, hs);
    wprep_kernel<<<(3 * D * D + 255) / 256, 256, 0, stream>>>(W1, W2, W3, wt);

    const float* bs[3] = {b1, b2, b3};
    dim3 ggrid(GRID_M, 2);
    for (int l = 0; l < 3; ++l) {
        bool last = (l == 2);
        agg_kernel<<<((size_t)N * 64 + 255) / 256, 256, 0, stream>>>(
            row_ptr, csr_src, hs, agg_h, agg_l);
        gemm_mfma_kernel<<<ggrid, 256, 0, stream>>>(
            agg_h, agg_l, wt + (size_t)l * 2 * D * D, bs[l], norm_dst,
            last ? nullptr : norm_src,
            last ? out : hs);
    }
}

// Round 8
// 398.223 us; speedup vs baseline: 1.0049x; 1.0049x over previous
//
#include <hip/hip_runtime.h>
#include <math.h>

typedef float f4 __attribute__((ext_vector_type(4)));
typedef float f32x4 __attribute__((ext_vector_type(4)));
typedef short s8 __attribute__((ext_vector_type(8)));  // 8 bf16 (4 VGPRs)
typedef short s4 __attribute__((ext_vector_type(4)));  // 4 bf16 (2 VGPRs)

static constexpr int N = 50000;
static constexpr int E = 800000;
static constexpr int D = 128;
static constexpr int SCAN_NB = (N + 255) / 256;        // 196
static constexpr int MBLK = 64;                        // gemm rows/block
static constexpr int GRID_M = (N + MBLK - 1) / MBLK;   // 782
static constexpr int N_PAD = GRID_M * MBLK;            // 50048
static constexpr int WT_PITCH = 136;                   // LDS pad: 272 B rows, 16B-aligned

__device__ inline unsigned short f32_bf16_rne(float x) {
    unsigned u = __float_as_uint(x);
    return (unsigned short)((u + 0x7FFF + ((u >> 16) & 1)) >> 16);
}
__device__ inline float bf16_f32(unsigned short h) {
    return __uint_as_float((unsigned)h << 16);
}

// --- int degree histogram ---
__global__ void deg_kernel(const int* __restrict__ src, const int* __restrict__ dst,
                           int* __restrict__ deg_out, int* __restrict__ deg_in) {
    int e = blockIdx.x * 256 + threadIdx.x;
    if (e < E) {
        atomicAdd(&deg_out[src[e]], 1);
        atomicAdd(&deg_in[dst[e]], 1);
    }
}

// --- norms from int degrees ---
__global__ void norm_kernel(const int* __restrict__ deg_out, const int* __restrict__ deg_in,
                            float* __restrict__ norm_src, float* __restrict__ norm_dst) {
    int i = blockIdx.x * 256 + threadIdx.x;
    if (i < N) {
        norm_src[i] = rsqrtf(fmaxf((float)deg_out[i], 1.0f));
        norm_dst[i] = rsqrtf(fmaxf((float)deg_in[i], 1.0f));
    }
}

// --- scan pass 1: per-block sums ---
__global__ __launch_bounds__(256) void scan_bsum_kernel(const int* __restrict__ deg,
                                                        int* __restrict__ bsums) {
    int i = blockIdx.x * 256 + threadIdx.x;
    int v = (i < N) ? deg[i] : 0;
#pragma unroll
    for (int off = 1; off < 64; off <<= 1) v += __shfl_xor(v, off, 64);
    __shared__ int ws[4];
    if ((threadIdx.x & 63) == 0) ws[threadIdx.x >> 6] = v;
    __syncthreads();
    if (threadIdx.x == 0) bsums[blockIdx.x] = ws[0] + ws[1] + ws[2] + ws[3];
}

// --- scan pass 2: exclusive scan of block sums ---
__global__ __launch_bounds__(256) void scan_bsums_kernel(int* __restrict__ bsums) {
    __shared__ int s[256];
    int t = threadIdx.x;
    s[t] = (t < SCAN_NB) ? bsums[t] : 0;
    __syncthreads();
    for (int off = 1; off < 256; off <<= 1) {
        int v = (t >= off) ? s[t - off] : 0;
        __syncthreads();
        s[t] += v;
        __syncthreads();
    }
    if (t < SCAN_NB) bsums[t] = (t == 0) ? 0 : s[t - 1];
}

// --- scan pass 3: rescan + offset -> row_ptr ---
__global__ __launch_bounds__(256) void scan_final_kernel(const int* __restrict__ deg,
                                                         const int* __restrict__ bsums,
                                                         int* __restrict__ row_ptr) {
    __shared__ int s[256];
    int b = blockIdx.x, t = threadIdx.x;
    int i = b * 256 + t;
    s[t] = (i < N) ? deg[i] : 0;
    __syncthreads();
    for (int off = 1; off < 256; off <<= 1) {
        int v = (t >= off) ? s[t - off] : 0;
        __syncthreads();
        s[t] += v;
        __syncthreads();
    }
    if (i < N) row_ptr[i + 1] = s[t] + bsums[b];
    if (i == 0) row_ptr[0] = 0;
}

// --- csr_src fill ---
__global__ void fill_kernel(const int* __restrict__ src, const int* __restrict__ dst,
                            const int* __restrict__ row_ptr, int* __restrict__ cursor,
                            int* __restrict__ csr_src) {
    int e = blockIdx.x * 256 + threadIdx.x;
    if (e < E) {
        int d = dst[e];
        int pos = row_ptr[d] + atomicAdd(&cursor[d], 1);
        csr_src[pos] = src[e];
    }
}

// --- hs[i] = emb[batch[i]] * norm_src[i] ---
__global__ void gather_kernel(const int* __restrict__ batch, const float* __restrict__ emb,
                              const float* __restrict__ norm_src, float* __restrict__ hs) {
    int gid = blockIdx.x * 256 + threadIdx.x;
    int i = gid >> 5;
    int c = (gid & 31) << 2;
    if (i < N) {
        float s = norm_src[i];
        f4 v = *(const f4*)(emb + (size_t)batch[i] * D + c);
        *(f4*)(hs + (size_t)i * D + c) = v * s;
    }
}

// --- agg: gather-sum hs rows, then split result to bf16 hi/lo for the MFMA gemm ---
__global__ void agg_kernel(const int* __restrict__ row_ptr, const int* __restrict__ csr_src,
                           const float* __restrict__ hs,
                           short* __restrict__ agg_h, short* __restrict__ agg_l) {
    int gid = blockIdx.x * 256 + threadIdx.x;
    int node = gid >> 6;
    if (node >= N) return;
    int lane = threadIdx.x & 63;
    int grp = lane >> 5;
    int col = (lane & 31) << 2;
    int beg = row_ptr[node], end = row_ptr[node + 1];

    f4 a0 = (f4)0.0f, a1 = (f4)0.0f, a2 = (f4)0.0f, a3 = (f4)0.0f;
    f4 a4 = (f4)0.0f, a5 = (f4)0.0f, a6 = (f4)0.0f, a7 = (f4)0.0f;
    int e = beg + grp;
    for (; e + 14 < end; e += 16) {
        int s0 = csr_src[e];
        int s1 = csr_src[e + 2];
        int s2 = csr_src[e + 4];
        int s3 = csr_src[e + 6];
        int s4 = csr_src[e + 8];
        int s5 = csr_src[e + 10];
        int s6 = csr_src[e + 12];
        int s7 = csr_src[e + 14];
        a0 += *(const f4*)(hs + (size_t)s0 * D + col);
        a1 += *(const f4*)(hs + (size_t)s1 * D + col);
        a2 += *(const f4*)(hs + (size_t)s2 * D + col);
        a3 += *(const f4*)(hs + (size_t)s3 * D + col);
        a4 += *(const f4*)(hs + (size_t)s4 * D + col);
        a5 += *(const f4*)(hs + (size_t)s5 * D + col);
        a6 += *(const f4*)(hs + (size_t)s6 * D + col);
        a7 += *(const f4*)(hs + (size_t)s7 * D + col);
    }
    for (; e < end; e += 2)
        a0 += *(const f4*)(hs + (size_t)csr_src[e] * D + col);
    a0 += a1; a2 += a3; a4 += a5; a6 += a7;
    a0 += a2; a4 += a6;
    a0 += a4;

    f4 o;
#pragma unroll
    for (int j = 0; j < 4; ++j)
        o[j] = a0[j] + __shfl_xor(a0[j], 32, 64);
    if (grp == 0) {
        s4 oh, ol;
#pragma unroll
        for (int j = 0; j < 4; ++j) {
            unsigned short h = f32_bf16_rne(o[j]);
            oh[j] = (short)h;
            ol[j] = (short)f32_bf16_rne(o[j] - bf16_f32(h));
        }
        *(s4*)(agg_h + (size_t)node * D + col) = oh;
        *(s4*)(agg_l + (size_t)node * D + col) = ol;
    }
}

// --- W prep: wt[layer][hi/lo][n][k] = bf16 split of W[k][n] (transposed, n-major) ---
__global__ void wprep_kernel(const float* __restrict__ W1, const float* __restrict__ W2,
                             const float* __restrict__ W3, short* __restrict__ wt) {
    int idx = blockIdx.x * 256 + threadIdx.x;
    if (idx >= 3 * D * D) return;
    int l = idx >> 14;          // layer
    int e = idx & (D * D - 1);
    int n = e >> 7, k = e & 127;
    const float* W = (l == 0) ? W1 : ((l == 1) ? W2 : W3);
    float w = W[(size_t)k * D + n];
    unsigned short h = f32_bf16_rne(w);
    unsigned short lo = f32_bf16_rne(w - bf16_f32(h));
    wt[(size_t)l * 2 * D * D + (size_t)n * D + k] = (short)h;
    wt[(size_t)l * 2 * D * D + D * D + (size_t)n * D + k] = (short)lo;
}

// --- MFMA GEMM: full 128 cols per block; 64 rows; 4 waves (16 rows each).
// A pre-split bf16 hi/lo (loaded once per row); W hi/lo staged in LDS (69.6 KB).
// 3-term split: C = Ah@Wh + Al@Wh + Ah@Wl.
__global__ __launch_bounds__(256, 2) void gemm_mfma_kernel(
    const short* __restrict__ Ah, const short* __restrict__ Al,
    const short* __restrict__ wth,
    const float* __restrict__ bias, const float* __restrict__ norm_dst,
    const float* __restrict__ post, float* __restrict__ out) {
    __shared__ short wt_h[D * WT_PITCH];   // 34816 B
    __shared__ short wt_l[D * WT_PITCH];   // 34816 B

    int tid = threadIdx.x;
    const short* gh = wth;                 // hi [n][k], n-major, 128x128
    const short* gl = wth + (size_t)D * D; // lo

#pragma unroll
    for (int it = 0; it < 8; ++it) {
        int c = tid + it * 256;            // chunk of 8 shorts (2048 chunks)
        int n = c >> 4, kc = c & 15;
        *(s8*)(&wt_h[n * WT_PITCH + kc * 8]) = *(const s8*)(gh + (size_t)n * D + kc * 8);
        *(s8*)(&wt_l[n * WT_PITCH + kc * 8]) = *(const s8*)(gl + (size_t)n * D + kc * 8);
    }
    __syncthreads();

    int wv = tid >> 6;
    int lane = tid & 63;
    int lg = lane >> 4;                    // lane group 0..3 (k-slice)
    int lr = lane & 15;                    // row/col within 16-tile

    int arow = blockIdx.x * 64 + wv * 16 + lr;  // A row for this lane's fragments
    const short* ahp = Ah + (size_t)arow * D;
    const short* alp = Al + (size_t)arow * D;

    f32x4 acc[8];
#pragma unroll
    for (int nt = 0; nt < 8; ++nt) acc[nt] = (f32x4)0.0f;

#pragma unroll
    for (int kt = 0; kt < 4; ++kt) {
        int ko = kt * 32 + lg * 8;
        s8 ah = *(const s8*)(ahp + ko);
        s8 al = *(const s8*)(alp + ko);
#pragma unroll
        for (int nt = 0; nt < 8; ++nt) {
            int bidx = (nt * 16 + lr) * WT_PITCH + ko;
            s8 bh = *(const s8*)(&wt_h[bidx]);
            s8 bl = *(const s8*)(&wt_l[bidx]);
            acc[nt] = __builtin_amdgcn_mfma_f32_16x16x32_bf16(ah, bh, acc[nt], 0, 0, 0);
            acc[nt] = __builtin_amdgcn_mfma_f32_16x16x32_bf16(al, bh, acc[nt], 0, 0, 0);
            acc[nt] = __builtin_amdgcn_mfma_f32_16x16x32_bf16(ah, bl, acc[nt], 0, 0, 0);
        }
    }

    // epilogue: C[row = wv*16 + lg*4 + i][col = nt*16 + lr]
    int r0 = blockIdx.x * 64 + wv * 16 + lg * 4;
    float nd[4], ps[4];
#pragma unroll
    for (int i = 0; i < 4; ++i) {
        int gr = r0 + i;
        nd[i] = (gr < N) ? norm_dst[gr] : 0.0f;
        ps[i] = (gr < N) ? (post ? post[gr] : 1.0f) : 0.0f;
    }
#pragma unroll
    for (int nt = 0; nt < 8; ++nt) {
        int col = nt * 16 + lr;
        float bv = bias[col];
#pragma unroll
        for (int i = 0; i < 4; ++i) {
            int gr = r0 + i;
            if (gr < N) {
                float v = fmaxf(acc[nt][i] * nd[i] + bv, 0.0f) * ps[i];
                out[(size_t)gr * D + col] = v;
            }
        }
    }
}

extern "C" void kernel_launch(void* const* d_in, const int* in_sizes, int n_in,
                              void* d_out, int out_size, void* d_ws, size_t ws_size,
                              hipStream_t stream) {
    const int*   batch = (const int*)d_in[0];
    const int*   src   = (const int*)d_in[1];
    const int*   dst   = (const int*)d_in[2];
    const float* emb   = (const float*)d_in[3];
    const float* W1    = (const float*)d_in[4];
    const float* b1    = (const float*)d_in[5];
    const float* W2    = (const float*)d_in[6];
    const float* b2    = (const float*)d_in[7];
    const float* W3    = (const float*)d_in[8];
    const float* b3    = (const float*)d_in[9];
    float* out = (float*)d_out;

    // ws layout (4B elems): norm_src[N] | norm_dst[N] | row_ptr[N+1] | csr_src[E]
    //                       | hs[N_PAD*D] | agg_h[N_PAD*D shorts] | agg_l[N_PAD*D shorts]
    //                       | wt (3*2*D*D shorts)
    // transient ints (deg_out, deg_in, cursor, bsums) alias the agg_h region.
    float* norm_src = (float*)d_ws;
    float* norm_dst = norm_src + N;
    int*   row_ptr  = (int*)(norm_dst + N);
    int*   csr_src  = row_ptr + (N + 1);
    float* hs       = (float*)(csr_src + E) + 3;  // 16B alignment
    short* agg_h    = (short*)(hs + (size_t)N_PAD * D);
    short* agg_l    = agg_h + (size_t)N_PAD * D;
    short* wt       = agg_l + (size_t)N_PAD * D;
    int*   deg_out  = (int*)agg_h;   // transient
    int*   deg_in   = deg_out + N;
    int*   cursor   = deg_in + N;
    int*   bsums    = cursor + N;

    hipMemsetAsync(deg_out, 0, 3 * (size_t)N * sizeof(int), stream);
    deg_kernel<<<(E + 255) / 256, 256, 0, stream>>>(src, dst, deg_out, deg_in);
    norm_kernel<<<(N + 255) / 256, 256, 0, stream>>>(deg_out, deg_in, norm_src, norm_dst);
    scan_bsum_kernel<<<SCAN_NB, 256, 0, stream>>>(deg_in, bsums);
    scan_bsums_kernel<<<1, 256, 0, stream>>>(bsums);
    scan_final_kernel<<<SCAN_NB, 256, 0, stream>>>(deg_in, bsums, row_ptr);
    fill_kernel<<<(E + 255) / 256, 256, 0, stream>>>(src, dst, row_ptr, cursor, csr_src);
    gather_kernel<<<((size_t)N * 32 + 255) / 256, 256, 0, stream>>>(batch, emb, norm_src, hs);
    wprep_kernel<<<(3 * D * D + 255) / 256, 256, 0, stream>>>(W1, W2, W3, wt);

    const float* bs[3] = {b1, b2, b3};
    for (int l = 0; l < 3; ++l) {
        bool last = (l == 2);
        agg_kernel<<<((size_t)N * 64 + 255) / 256, 256, 0, stream>>>(
            row_ptr, csr_src, hs, agg_h, agg_l);
        gemm_mfma_kernel<<<GRID_M, 256, 0, stream>>>(
            agg_h, agg_l, wt + (size_t)l * 2 * D * D, bs[l], norm_dst,
            last ? nullptr : norm_src,
            last ? out : hs);
    }
}

// Round 9
// 394.211 us; speedup vs baseline: 1.0151x; 1.0102x over previous
//
#include <hip/hip_runtime.h>
#include <math.h>

typedef float f4 __attribute__((ext_vector_type(4)));
typedef float f32x4 __attribute__((ext_vector_type(4)));
typedef short s8 __attribute__((ext_vector_type(8)));  // 8 bf16 (4 VGPRs)
typedef short s4 __attribute__((ext_vector_type(4)));  // 4 bf16 (2 VGPRs)

static constexpr int N = 50000;
static constexpr int E = 800000;
static constexpr int D = 128;
static constexpr int SCAN_NB = (N + 255) / 256;        // 196
static constexpr int MBLK = 64;                        // gemm rows/block
static constexpr int GRID_M = (N + MBLK - 1) / MBLK;   // 782
static constexpr int N_PAD = GRID_M * MBLK;            // 50048
static constexpr int WT_PITCH = 136;                   // LDS pad
static constexpr int AGG_NB = N / 4;                   // 12500 node-blocks (4 nodes each)
static constexpr int AGG_GRID = AGG_NB * 2;            // 25000 (x2 column halves)

__device__ inline unsigned short f32_bf16_rne(float x) {
    unsigned u = __float_as_uint(x);
    return (unsigned short)((u + 0x7FFF + ((u >> 16) & 1)) >> 16);
}
__device__ inline float bf16_f32(unsigned short h) {
    return __uint_as_float((unsigned)h << 16);
}

// --- int degree histogram ---
__global__ void deg_kernel(const int* __restrict__ src, const int* __restrict__ dst,
                           int* __restrict__ deg_out, int* __restrict__ deg_in) {
    int e = blockIdx.x * 256 + threadIdx.x;
    if (e < E) {
        atomicAdd(&deg_out[src[e]], 1);
        atomicAdd(&deg_in[dst[e]], 1);
    }
}

// --- scan pass 1 (+ fused norm compute): per-block sums of deg_in ---
__global__ __launch_bounds__(256) void scan_bsum_norm_kernel(
    const int* __restrict__ deg_out, const int* __restrict__ deg_in,
    float* __restrict__ norm_src, float* __restrict__ norm_dst,
    int* __restrict__ bsums) {
    int i = blockIdx.x * 256 + threadIdx.x;
    int v = 0;
    if (i < N) {
        norm_src[i] = rsqrtf(fmaxf((float)deg_out[i], 1.0f));
        norm_dst[i] = rsqrtf(fmaxf((float)deg_in[i], 1.0f));
        v = deg_in[i];
    }
#pragma unroll
    for (int off = 1; off < 64; off <<= 1) v += __shfl_xor(v, off, 64);
    __shared__ int ws[4];
    if ((threadIdx.x & 63) == 0) ws[threadIdx.x >> 6] = v;
    __syncthreads();
    if (threadIdx.x == 0) bsums[blockIdx.x] = ws[0] + ws[1] + ws[2] + ws[3];
}

// --- scan pass 2: exclusive scan of block sums ---
__global__ __launch_bounds__(256) void scan_bsums_kernel(int* __restrict__ bsums) {
    __shared__ int s[256];
    int t = threadIdx.x;
    s[t] = (t < SCAN_NB) ? bsums[t] : 0;
    __syncthreads();
    for (int off = 1; off < 256; off <<= 1) {
        int v = (t >= off) ? s[t - off] : 0;
        __syncthreads();
        s[t] += v;
        __syncthreads();
    }
    if (t < SCAN_NB) bsums[t] = (t == 0) ? 0 : s[t - 1];
}

// --- scan pass 3: rescan + offset -> row_ptr ---
__global__ __launch_bounds__(256) void scan_final_kernel(const int* __restrict__ deg,
                                                         const int* __restrict__ bsums,
                                                         int* __restrict__ row_ptr) {
    __shared__ int s[256];
    int b = blockIdx.x, t = threadIdx.x;
    int i = b * 256 + t;
    s[t] = (i < N) ? deg[i] : 0;
    __syncthreads();
    for (int off = 1; off < 256; off <<= 1) {
        int v = (t >= off) ? s[t - off] : 0;
        __syncthreads();
        s[t] += v;
        __syncthreads();
    }
    if (i < N) row_ptr[i + 1] = s[t] + bsums[b];
    if (i == 0) row_ptr[0] = 0;
}

// --- csr fill: src id + batch id + src-norm per edge slot ---
__global__ void fill_kernel(const int* __restrict__ src, const int* __restrict__ dst,
                            const int* __restrict__ batch, const float* __restrict__ norm_src,
                            const int* __restrict__ row_ptr, int* __restrict__ cursor,
                            int* __restrict__ csr_src, int* __restrict__ csr_batch,
                            float* __restrict__ csr_norm) {
    int e = blockIdx.x * 256 + threadIdx.x;
    if (e < E) {
        int s = src[e];
        int d = dst[e];
        int pos = row_ptr[d] + atomicAdd(&cursor[d], 1);
        csr_src[pos] = s;
        csr_batch[pos] = batch[s];
        csr_norm[pos] = norm_src[s];
    }
}

// --- agg: per (node, col-half) gather-sum of table rows, bf16 hi/lo output.
// Column halves routed to disjoint XCD groups via bid%8 round-robin heuristic:
// bids 0-3 (XCD 0-3) -> half 0, bids 4-7 (XCD 4-7) -> half 1. Per-XCD gather
// footprint halves (25.6 -> 12.8 MB) for better L2 hit rate. Correct under any
// actual block->XCD mapping.
// Wave = 1 node: 4 edge-groups x 16 lanes (f4 cols), 4-deep unrolled gathers.
// escale != null (layer 1): acc += table[idx[e]] * escale[e]  (emb path).
__global__ void agg_kernel(const int* __restrict__ row_ptr, const int* __restrict__ idx,
                           const float* __restrict__ escale, const float* __restrict__ table,
                           short* __restrict__ agg_h, short* __restrict__ agg_l) {
    int bid = blockIdx.x;
    int nodeblk = (bid >> 3) * 4 + (bid & 3);
    int half = (bid >> 2) & 1;
    int node = nodeblk * 4 + (threadIdx.x >> 6);
    int lane = threadIdx.x & 63;
    int grp = lane >> 4;                     // edge group 0..3
    int col = half * 64 + (lane & 15) * 4;   // f4 column slice
    int beg = row_ptr[node], end = row_ptr[node + 1];

    f4 a0 = (f4)0.0f, a1 = (f4)0.0f, a2 = (f4)0.0f, a3 = (f4)0.0f;
    int e = beg + grp;
    if (escale) {
        for (; e + 12 < end; e += 16) {
            int s0 = idx[e], s1 = idx[e + 4], s2 = idx[e + 8], s3 = idx[e + 12];
            float w0 = escale[e], w1 = escale[e + 4];
            float w2 = escale[e + 8], w3 = escale[e + 12];
            a0 += *(const f4*)(table + (size_t)s0 * D + col) * w0;
            a1 += *(const f4*)(table + (size_t)s1 * D + col) * w1;
            a2 += *(const f4*)(table + (size_t)s2 * D + col) * w2;
            a3 += *(const f4*)(table + (size_t)s3 * D + col) * w3;
        }
        for (; e < end; e += 4)
            a0 += *(const f4*)(table + (size_t)idx[e] * D + col) * escale[e];
    } else {
        for (; e + 12 < end; e += 16) {
            int s0 = idx[e], s1 = idx[e + 4], s2 = idx[e + 8], s3 = idx[e + 12];
            a0 += *(const f4*)(table + (size_t)s0 * D + col);
            a1 += *(const f4*)(table + (size_t)s1 * D + col);
            a2 += *(const f4*)(table + (size_t)s2 * D + col);
            a3 += *(const f4*)(table + (size_t)s3 * D + col);
        }
        for (; e < end; e += 4)
            a0 += *(const f4*)(table + (size_t)idx[e] * D + col);
    }
    a0 += a1; a2 += a3; a0 += a2;

    f4 o;
#pragma unroll
    for (int j = 0; j < 4; ++j) {
        float v = a0[j];
        v += __shfl_xor(v, 16, 64);
        v += __shfl_xor(v, 32, 64);
        o[j] = v;
    }
    if (grp == 0) {
        s4 oh, ol;
#pragma unroll
        for (int j = 0; j < 4; ++j) {
            unsigned short h = f32_bf16_rne(o[j]);
            oh[j] = (short)h;
            ol[j] = (short)f32_bf16_rne(o[j] - bf16_f32(h));
        }
        *(s4*)(agg_h + (size_t)node * D + col) = oh;
        *(s4*)(agg_l + (size_t)node * D + col) = ol;
    }
}

// --- W prep: wt[layer][hi/lo][n][k] = bf16 split of W[k][n] (transposed, n-major) ---
__global__ void wprep_kernel(const float* __restrict__ W1, const float* __restrict__ W2,
                             const float* __restrict__ W3, short* __restrict__ wt) {
    int idx = blockIdx.x * 256 + threadIdx.x;
    if (idx >= 3 * D * D) return;
    int l = idx >> 14;          // layer
    int e = idx & (D * D - 1);
    int n = e >> 7, k = e & 127;
    const float* W = (l == 0) ? W1 : ((l == 1) ? W2 : W3);
    float w = W[(size_t)k * D + n];
    unsigned short h = f32_bf16_rne(w);
    unsigned short lo = f32_bf16_rne(w - bf16_f32(h));
    wt[(size_t)l * 2 * D * D + (size_t)n * D + k] = (short)h;
    wt[(size_t)l * 2 * D * D + D * D + (size_t)n * D + k] = (short)lo;
}

// --- MFMA GEMM: full 128 cols per block; 64 rows; 4 waves (16 rows each).
// 3-term split: C = Ah@Wh + Al@Wh + Ah@Wl.
__global__ __launch_bounds__(256, 2) void gemm_mfma_kernel(
    const short* __restrict__ Ah, const short* __restrict__ Al,
    const short* __restrict__ wth,
    const float* __restrict__ bias, const float* __restrict__ norm_dst,
    const float* __restrict__ post, float* __restrict__ out) {
    __shared__ short wt_h[D * WT_PITCH];   // 34816 B
    __shared__ short wt_l[D * WT_PITCH];   // 34816 B

    int tid = threadIdx.x;
    const short* gh = wth;
    const short* gl = wth + (size_t)D * D;

#pragma unroll
    for (int it = 0; it < 8; ++it) {
        int c = tid + it * 256;
        int n = c >> 4, kc = c & 15;
        *(s8*)(&wt_h[n * WT_PITCH + kc * 8]) = *(const s8*)(gh + (size_t)n * D + kc * 8);
        *(s8*)(&wt_l[n * WT_PITCH + kc * 8]) = *(const s8*)(gl + (size_t)n * D + kc * 8);
    }
    __syncthreads();

    int wv = tid >> 6;
    int lane = tid & 63;
    int lg = lane >> 4;
    int lr = lane & 15;

    int arow = blockIdx.x * 64 + wv * 16 + lr;
    const short* ahp = Ah + (size_t)arow * D;
    const short* alp = Al + (size_t)arow * D;

    f32x4 acc[8];
#pragma unroll
    for (int nt = 0; nt < 8; ++nt) acc[nt] = (f32x4)0.0f;

#pragma unroll
    for (int kt = 0; kt < 4; ++kt) {
        int ko = kt * 32 + lg * 8;
        s8 ah = *(const s8*)(ahp + ko);
        s8 al = *(const s8*)(alp + ko);
#pragma unroll
        for (int nt = 0; nt < 8; ++nt) {
            int bidx = (nt * 16 + lr) * WT_PITCH + ko;
            s8 bh = *(const s8*)(&wt_h[bidx]);
            s8 bl = *(const s8*)(&wt_l[bidx]);
            acc[nt] = __builtin_amdgcn_mfma_f32_16x16x32_bf16(ah, bh, acc[nt], 0, 0, 0);
            acc[nt] = __builtin_amdgcn_mfma_f32_16x16x32_bf16(al, bh, acc[nt], 0, 0, 0);
            acc[nt] = __builtin_amdgcn_mfma_f32_16x16x32_bf16(ah, bl, acc[nt], 0, 0, 0);
        }
    }

    int r0 = blockIdx.x * 64 + wv * 16 + lg * 4;
    float nd[4], ps[4];
#pragma unroll
    for (int i = 0; i < 4; ++i) {
        int gr = r0 + i;
        nd[i] = (gr < N) ? norm_dst[gr] : 0.0f;
        ps[i] = (gr < N) ? (post ? post[gr] : 1.0f) : 0.0f;
    }
#pragma unroll
    for (int nt = 0; nt < 8; ++nt) {
        int col = nt * 16 + lr;
        float bv = bias[col];
#pragma unroll
        for (int i = 0; i < 4; ++i) {
            int gr = r0 + i;
            if (gr < N) {
                float v = fmaxf(acc[nt][i] * nd[i] + bv, 0.0f) * ps[i];
                out[(size_t)gr * D + col] = v;
            }
        }
    }
}

extern "C" void kernel_launch(void* const* d_in, const int* in_sizes, int n_in,
                              void* d_out, int out_size, void* d_ws, size_t ws_size,
                              hipStream_t stream) {
    const int*   batch = (const int*)d_in[0];
    const int*   src   = (const int*)d_in[1];
    const int*   dst   = (const int*)d_in[2];
    const float* emb   = (const float*)d_in[3];
    const float* W1    = (const float*)d_in[4];
    const float* b1    = (const float*)d_in[5];
    const float* W2    = (const float*)d_in[6];
    const float* b2    = (const float*)d_in[7];
    const float* W3    = (const float*)d_in[8];
    const float* b3    = (const float*)d_in[9];
    float* out = (float*)d_out;

    // ws layout (4B elems): norm_src[N] | norm_dst[N] | row_ptr[N+1] | csr_src[E]
    //                       | hs[N_PAD*D] | agg_h[N_PAD*D sh] | agg_l[N_PAD*D sh] | wt
    // Overlays: csr_batch/csr_norm live in the hs region (dead until gemm L1 writes
    // it, which happens after their last read in agg L1; fill rewrites every entry
    // each call). deg_out/deg_in/cursor/bsums live in agg_h (dead until agg L1).
    float* norm_src  = (float*)d_ws;
    float* norm_dst  = norm_src + N;
    int*   row_ptr   = (int*)(norm_dst + N);
    int*   csr_src   = row_ptr + (N + 1);
    float* hs        = (float*)(csr_src + E) + 3;  // 16B alignment
    short* agg_h     = (short*)(hs + (size_t)N_PAD * D);
    short* agg_l     = agg_h + (size_t)N_PAD * D;
    short* wt        = agg_l + (size_t)N_PAD * D;
    int*   csr_batch = (int*)hs;        // overlay (first E elems of hs)
    float* csr_norm  = hs + E;          // overlay (next E elems of hs)
    int*   deg_out   = (int*)agg_h;     // transients in agg_h region
    int*   deg_in    = deg_out + N;
    int*   cursor    = deg_in + N;
    int*   bsums     = cursor + N;

    hipMemsetAsync(deg_out, 0, 3 * (size_t)N * sizeof(int), stream);
    deg_kernel<<<(E + 255) / 256, 256, 0, stream>>>(src, dst, deg_out, deg_in);
    scan_bsum_norm_kernel<<<SCAN_NB, 256, 0, stream>>>(deg_out, deg_in,
                                                       norm_src, norm_dst, bsums);
    scan_bsums_kernel<<<1, 256, 0, stream>>>(bsums);
    scan_final_kernel<<<SCAN_NB, 256, 0, stream>>>(deg_in, bsums, row_ptr);
    fill_kernel<<<(E + 255) / 256, 256, 0, stream>>>(src, dst, batch, norm_src,
                                                     row_ptr, cursor,
                                                     csr_src, csr_batch, csr_norm);
    wprep_kernel<<<(3 * D * D + 255) / 256, 256, 0, stream>>>(W1, W2, W3, wt);

    const float* bs[3] = {b1, b2, b3};
    for (int l = 0; l < 3; ++l) {
        bool last = (l == 2);
        if (l == 0) {
            // layer 1: gather emb rows directly (hs never materialized)
            agg_kernel<<<AGG_GRID, 256, 0, stream>>>(
                row_ptr, csr_batch, csr_norm, emb, agg_h, agg_l);
        } else {
            agg_kernel<<<AGG_GRID, 256, 0, stream>>>(
                row_ptr, csr_src, nullptr, hs, agg_h, agg_l);
        }
        gemm_mfma_kernel<<<GRID_M, 256, 0, stream>>>(
            agg_h, agg_l, wt + (size_t)l * 2 * D * D, bs[l], norm_dst,
            last ? nullptr : norm_src,
            last ? out : hs);
    }
}